// Round 17
// baseline (865.273 us; speedup 1.0000x reference)
//
#include <hip/hip_runtime.h>

#define NTOK 65536
#define DIMD 256
#define VOC  1024
#define NLEV 4
#define TAUP 0.056f   // screened top-2 gap below this -> exact resolution

typedef __attribute__((ext_vector_type(8))) _Float16 f16x8;
typedef __attribute__((ext_vector_type(4))) float f32x4;

// ---------------------------------------------------------------------------
// ws layout:
//   [0]        double loss_acc
//   [8]        int    cnts[8]
//   [64]       float  wnorm[NLEV][VOC]     (16 KB)
//   [16448]    u16    idx[NLEV][NTOK]      (512 KB)
//   [540736]   int    flist[NTOK]          (256 KB)
//   [802880]   int2   plist[NTOK]          (512 KB)
//   [1327168]  uint4  wimg[NLEV*16*2048]   (2 MB)  f16 W, phase-tile order
// Residual never materialized: rebuilt as fl-chain(latent - q0 - ...).
// wimg tile P (codes P*64..+64): 2048 uint4; slot s: frag fi=s>>6 (n=fi>>3,
// k=fi&7), lane=s&63 holds W[P*64+n*16+(lane&15)][k*32+(lane>>4)*8..+8] f16x8.
// ---------------------------------------------------------------------------

__device__ __forceinline__ uint4 cvt8_f16_u(const float4 x0, const float4 x1) {
    union { f16x8 h; uint4 u; } r;
    r.h[0] = (_Float16)x0.x; r.h[1] = (_Float16)x0.y;
    r.h[2] = (_Float16)x0.z; r.h[3] = (_Float16)x0.w;
    r.h[4] = (_Float16)x1.x; r.h[5] = (_Float16)x1.y;
    r.h[6] = (_Float16)x1.z; r.h[7] = (_Float16)x1.w;
    return r.u;
}

__device__ __forceinline__ f16x8 cvt8_f16(const float4 x0, const float4 x1) {
    union { f16x8 h; uint4 u; } r;
    r.h[0] = (_Float16)x0.x; r.h[1] = (_Float16)x0.y;
    r.h[2] = (_Float16)x0.z; r.h[3] = (_Float16)x0.w;
    r.h[4] = (_Float16)x1.x; r.h[5] = (_Float16)x1.y;
    r.h[6] = (_Float16)x1.z; r.h[7] = (_Float16)x1.w;
    return r.h;
}

__device__ __forceinline__ f16x8 u2h(uint4 u) {
    union { uint4 u; f16x8 h; } r; r.u = u; return r.h;
}

__device__ __forceinline__ void gl_lds16(const uint4* g, uint4* l) {
    __builtin_amdgcn_global_load_lds(
        (const __attribute__((address_space(1))) unsigned*)g,
        (__attribute__((address_space(3))) unsigned*)l, 16, 0, 0);
}

__device__ __forceinline__ unsigned med3u(unsigned a, unsigned b, unsigned c) {
    unsigned d;
    asm("v_med3_u32 %0, %1, %2, %3" : "=v"(d) : "v"(a), "v"(b), "v"(c));
    return d;
}

// merge two ascending u32 triples with (value, idx) lexicographic order
__device__ __forceinline__ void merge3u(unsigned& a1, unsigned& a2, unsigned& a3,
                                        int& ai1, int& ai2,
                                        unsigned o1, unsigned o2, unsigned o3,
                                        int oi1, int oi2)
{
    const bool sw = (o1 < a1) || (o1 == a1 && oi1 < ai1);
    const unsigned b1 = sw ? o1 : a1; const int bi1 = sw ? oi1 : ai1;
    const unsigned c1 = sw ? a1 : o1; const int ci1 = sw ? ai1 : oi1;
    const unsigned b2 = sw ? o2 : a2; const int bi2 = sw ? oi2 : ai2;
    const unsigned c2 = sw ? a2 : o2;
    const unsigned b3 = sw ? o3 : a3;
    a1 = b1; ai1 = bi1;
    if (c1 < b2 || (c1 == b2 && ci1 < bi2)) {
        a2 = c1; ai2 = ci1; a3 = min(b2, c2);
    } else {
        a2 = b2; ai2 = bi2; a3 = min(b3, c1);
    }
}

// ---------- pre-convert W into phase-tile-ordered f16 image -----------------
__global__ void k_wsplit(const float* __restrict__ emb, uint4* __restrict__ wimg,
                         int* cnts)
{
    if (blockIdx.x == 0 && threadIdx.x < 8) cnts[threadIdx.x] = 0;
    const int l = blockIdx.x >> 4, P = blockIdx.x & 15;   // grid = NLEV*16
    const int tid = threadIdx.x;
    #pragma unroll
    for (int i = 0; i < 8; ++i) {
        const int s  = tid + i * 256;        // 0..2047
        const int fi = s >> 6, ls = s & 63;
        const int n = fi >> 3, k = fi & 7;
        const int code = P * 64 + n * 16 + (ls & 15);
        const float* src = emb + ((size_t)(l * VOC + code)) * DIMD + k * 32 + (ls >> 4) * 8;
        const float4 x0 = *reinterpret_cast<const float4*>(src);
        const float4 x1 = *reinterpret_cast<const float4*>(src + 4);
        wimg[((size_t)(l * 16 + P)) * 2048 + s] = cvt8_f16_u(x0, x1);
    }
}

// ------------------- numpy pairwise sum-of-squares (16-lane) ----------------
__device__ __forceinline__ float np_pairnorm_row(const float* row, int j)
{
#pragma clang fp contract(off)
    const int half = j >> 3;
    const int jj   = j & 7;
    const float* a = row + half * 128 + jj;
    float r = a[0] * a[0];
    #pragma unroll
    for (int i = 1; i < 16; ++i) {
        const float x  = a[8 * i];
        const float sq = x * x;
        r = r + sq;
    }
    r = r + __shfl_xor(r, 1);
    r = r + __shfl_xor(r, 2);
    r = r + __shfl_xor(r, 4);
    r = r + __shfl_xor(r, 8);
    return r;
}

__global__ void k_pairnorm(const float* src, float* __restrict__ dst,
                           int nrows, double* loss_acc)
{
    if (loss_acc && blockIdx.x == 0 && threadIdx.x == 0) *loss_acc = 0.0;
    const int gtid  = blockIdx.x * blockDim.x + threadIdx.x;
    const int gwave = gtid >> 6;
    const int lane  = threadIdx.x & 63;
    const int nwave = (gridDim.x * blockDim.x) >> 6;
    const int sub   = lane >> 4;
    const int j     = lane & 15;
    for (int r4 = gwave; r4 * 4 < nrows; r4 += nwave) {
        const int row = r4 * 4 + sub;
        const float v = np_pairnorm_row(src + (size_t)row * DIMD, j);
        if (j == 0) dst[row] = v;
    }
}

#define MFMA16(A, B, C) __builtin_amdgcn_mfma_f32_16x16x32_f16((A), (B), (C), 0, 0, 0)

// ------------- screen (R14 verbatim): LDS dbuf + counted vmcnt --------------
template<int LVL>
__global__ __launch_bounds__(256, 2)
void k_screen(const float* __restrict__ latent, const float* __restrict__ emb,
              const unsigned short* __restrict__ idx_all,
              const uint4* __restrict__ wimg_l, const float* __restrict__ wnorml,
              unsigned short* __restrict__ idxl, int2* __restrict__ plist,
              int* __restrict__ flist, int* cnts_l, double* loss_acc)
{
    __shared__ uint4 ldsB[2][2048];   // 64 KB double-buffered B tile

    const int tid = threadIdx.x, lane = tid & 63, w = tid >> 6;
    const int lr = lane & 15, lg = lane >> 4;
    const int wbase = blockIdx.x * 128 + w * 32;

#define STAGE(pp_, buf_) { \
    const uint4* src_ = wimg_l + (size_t)(pp_) * 2048; \
    _Pragma("unroll") \
    for (int i_ = 0; i_ < 8; ++i_) \
        gl_lds16(src_ + tid + i_ * 256, &ldsB[buf_][tid + i_ * 256]); }

    STAGE(0, 0)

    f16x8 af0_0, af0_1, af0_2, af0_3, af0_4, af0_5, af0_6, af0_7;
    f16x8 af1_0, af1_1, af1_2, af1_3, af1_4, af1_5, af1_6, af1_7;
    float lsum = 0.0f;
    const int t0 = wbase + lr, t1 = wbase + 16 + lr;
    const float* lrow0 = latent + (size_t)t0 * DIMD;
    const float* lrow1 = latent + (size_t)t1 * DIMD;
    const float* qr0[LVL > 0 ? LVL : 1];
    const float* qr1[LVL > 0 ? LVL : 1];
    #pragma unroll
    for (int j = 0; j < LVL; ++j) {
        qr0[j] = emb + ((size_t)j * VOC + idx_all[j * NTOK + t0]) * DIMD;
        qr1[j] = emb + ((size_t)j * VOC + idx_all[j * NTOK + t1]) * DIMD;
    }

#define PRO(m_, dc_) { \
    const int off = (dc_) * 32 + lg * 8; \
    float4 x0 = *reinterpret_cast<const float4*>(lrow##m_ + off); \
    float4 x1 = *reinterpret_cast<const float4*>(lrow##m_ + off + 4); \
    _Pragma("unroll") \
    for (int j = 0; j < LVL; ++j) { \
        const float4 q0 = *reinterpret_cast<const float4*>(qr##m_[j] + off); \
        const float4 q1 = *reinterpret_cast<const float4*>(qr##m_[j] + off + 4); \
        x0.x -= q0.x; x0.y -= q0.y; x0.z -= q0.z; x0.w -= q0.w; \
        x1.x -= q1.x; x1.y -= q1.y; x1.z -= q1.z; x1.w -= q1.w; \
    } \
    if (LVL) { \
        lsum += x0.x * x0.x + x0.y * x0.y + x0.z * x0.z + x0.w * x0.w \
              + x1.x * x1.x + x1.y * x1.y + x1.z * x1.z + x1.w * x1.w; \
    } \
    af##m_##_##dc_ = cvt8_f16(x0, x1); }

    PRO(0, 0) PRO(0, 1) PRO(0, 2) PRO(0, 3) PRO(0, 4) PRO(0, 5) PRO(0, 6) PRO(0, 7)
    PRO(1, 0) PRO(1, 1) PRO(1, 2) PRO(1, 3) PRO(1, 4) PRO(1, 5) PRO(1, 6) PRO(1, 7)
#undef PRO

    if (LVL) {
        #pragma unroll
        for (int o = 32; o; o >>= 1) lsum += __shfl_down(lsum, o);
        if (lane == 0) atomicAdd(loss_acc, (double)lsum);
    }

#define DECLK(m_, r_) unsigned k1_##m_##_##r_ = 0xFFFFFFFFu, \
    k2_##m_##_##r_ = 0xFFFFFFFFu, k3_##m_##_##r_ = 0xFFFFFFFFu;
    DECLK(0, 0) DECLK(0, 1) DECLK(0, 2) DECLK(0, 3)
    DECLK(1, 0) DECLK(1, 1) DECLK(1, 2) DECLK(1, 3)
#undef DECLK

    asm volatile("s_waitcnt vmcnt(0)" ::: "memory");
    __builtin_amdgcn_s_barrier();
    __builtin_amdgcn_sched_barrier(0);

#define KSTEP(k_) { \
    const f16x8 b0 = u2h(LB[((0 * 8) + k_) * 64 + lane]); \
    const f16x8 b1 = u2h(LB[((1 * 8) + k_) * 64 + lane]); \
    const f16x8 b2 = u2h(LB[((2 * 8) + k_) * 64 + lane]); \
    const f16x8 b3 = u2h(LB[((3 * 8) + k_) * 64 + lane]); \
    c00 = MFMA16(af0_##k_, b0, c00); c10 = MFMA16(af1_##k_, b0, c10); \
    c01 = MFMA16(af0_##k_, b1, c01); c11 = MFMA16(af1_##k_, b1, c11); \
    c02 = MFMA16(af0_##k_, b2, c02); c12 = MFMA16(af1_##k_, b2, c12); \
    c03 = MFMA16(af0_##k_, b3, c03); c13 = MFMA16(af1_##k_, b3, c13); }

#define LADD(k1_, k2_, k3_, sval_, cbn_) { \
    const unsigned key_ = (__float_as_uint(sval_) & 0xFFFFFFC0u) | (cbn_); \
    const unsigned nk3_ = med3u(key_, k2_, k3_); \
    const unsigned nk2_ = med3u(k1_, key_, k2_); \
    k1_ = min(k1_, key_); k2_ = nk2_; k3_ = nk3_; }

    for (int p = 0; p < 16; ++p) {
        const int cur = p & 1;
        if (p < 15) {
            STAGE(p + 1, cur ^ 1)
            asm volatile("s_waitcnt vmcnt(8)" ::: "memory");
        } else {
            asm volatile("s_waitcnt vmcnt(0)" ::: "memory");
        }
        __builtin_amdgcn_s_barrier();
        __builtin_amdgcn_sched_barrier(0);

        const uint4* LB = &ldsB[cur][0];
        f32x4 c00 = (f32x4)0.0f, c01 = (f32x4)0.0f, c02 = (f32x4)0.0f, c03 = (f32x4)0.0f;
        f32x4 c10 = (f32x4)0.0f, c11 = (f32x4)0.0f, c12 = (f32x4)0.0f, c13 = (f32x4)0.0f;

        __builtin_amdgcn_s_setprio(1);
        KSTEP(0) KSTEP(1) KSTEP(2) KSTEP(3) KSTEP(4) KSTEP(5) KSTEP(6) KSTEP(7)
        __builtin_amdgcn_s_setprio(0);

        const float wn0 = wnorml[p * 64 + 0 * 16 + lr] + 512.0f;
        const float wn1 = wnorml[p * 64 + 1 * 16 + lr] + 512.0f;
        const float wn2 = wnorml[p * 64 + 2 * 16 + lr] + 512.0f;
        const float wn3 = wnorml[p * 64 + 3 * 16 + lr] + 512.0f;
        const unsigned cb = (unsigned)(p * 4);
#define LADN(m_, cx_, wn_, n_) \
        LADD(k1_##m_##_0, k2_##m_##_0, k3_##m_##_0, fmaf(-2.0f, cx_[0], wn_), cb + n_) \
        LADD(k1_##m_##_1, k2_##m_##_1, k3_##m_##_1, fmaf(-2.0f, cx_[1], wn_), cb + n_) \
        LADD(k1_##m_##_2, k2_##m_##_2, k3_##m_##_2, fmaf(-2.0f, cx_[2], wn_), cb + n_) \
        LADD(k1_##m_##_3, k2_##m_##_3, k3_##m_##_3, fmaf(-2.0f, cx_[3], wn_), cb + n_)
        LADN(0, c00, wn0, 0) LADN(0, c01, wn1, 1) LADN(0, c02, wn2, 2) LADN(0, c03, wn3, 3)
        LADN(1, c10, wn0, 0) LADN(1, c11, wn1, 1) LADN(1, c12, wn2, 2) LADN(1, c13, wn3, 3)
#undef LADN

        asm volatile("s_waitcnt lgkmcnt(0)" ::: "memory");
        __builtin_amdgcn_sched_barrier(0);
        __builtin_amdgcn_s_barrier();
        __builtin_amdgcn_sched_barrier(0);
    }
#undef KSTEP
#undef LADD
#undef STAGE

    unsigned K1[2][4] = {{k1_0_0, k1_0_1, k1_0_2, k1_0_3},
                         {k1_1_0, k1_1_1, k1_1_2, k1_1_3}};
    unsigned K2[2][4] = {{k2_0_0, k2_0_1, k2_0_2, k2_0_3},
                         {k2_1_0, k2_1_1, k2_1_2, k2_1_3}};
    unsigned K3[2][4] = {{k3_0_0, k3_0_1, k3_0_2, k3_0_3},
                         {k3_1_0, k3_1_1, k3_1_2, k3_1_3}};
    #pragma unroll
    for (int m = 0; m < 2; ++m)
        #pragma unroll
        for (int r = 0; r < 4; ++r) {
            unsigned v1 = K1[m][r] & 0xFFFFFFC0u;
            unsigned v2 = K2[m][r] & 0xFFFFFFC0u;
            unsigned v3 = K3[m][r] & 0xFFFFFFC0u;
            int id1 = (int)((K1[m][r] & 63u) << 4) | lr;
            int id2 = (int)((K2[m][r] & 63u) << 4) | lr;
            #pragma unroll
            for (int d = 1; d < 16; d <<= 1) {
                const unsigned o1 = __shfl_xor(v1, d);
                const unsigned o2 = __shfl_xor(v2, d);
                const unsigned o3 = __shfl_xor(v3, d);
                const int     oi1 = __shfl_xor(id1, d);
                const int     oi2 = __shfl_xor(id2, d);
                merge3u(v1, v2, v3, id1, id2, o1, o2, o3, oi1, oi2);
            }
            if (lr == 0) {
                const int gt = wbase + m * 16 + lg * 4 + r;
                idxl[gt] = (unsigned short)id1;
                const float s1 = __uint_as_float(v1);
                const float s2 = __uint_as_float(v2);
                const float s3 = __uint_as_float(v3);
                if (s2 - s1 < TAUP) {
                    if (s3 - s1 >= TAUP) {
                        const int pp = atomicAdd(&cnts_l[1], 1);
                        plist[pp] = make_int2(gt, id1 | (id2 << 16));
                    } else {
                        const int pp = atomicAdd(&cnts_l[0], 1);
                        flist[pp] = gt;
                    }
                }
            }
        }
}

// ---- rescue: lane-parallel pair compare + per-wave full rescan -------------
// grid 768 x 256. Waves [0,2560): pair entries, 32/wave (2 lanes/entry).
// Waves [2560,3072): full rescans, 1 token/wave (LDS rbuf, wave-synchronous).
template<int LVL>
__global__ __launch_bounds__(256, 4)
void k_rescue(const float* __restrict__ latent, const float* __restrict__ emb,
              const unsigned short* __restrict__ idx_all,
              const float* __restrict__ wnorml,
              const int2* __restrict__ plist, const int* __restrict__ flist,
              const int* __restrict__ cnts_l,
              unsigned short* __restrict__ idxl)
{
    __shared__ float rbufs[4][DIMD];
    const int lane = threadIdx.x & 63;
    const int ww = blockIdx.x * 4 + (threadIdx.x >> 6);   // global wave id
    const float* embl = emb + (size_t)LVL * VOC * DIMD;

    if (ww < 2560) {
        // ---------------- pair path: lane i -> entry base+(i>>1), cand i&1 ---
        int cnt = cnts_l[1]; if (cnt > NTOK) cnt = NTOK;
        for (int base = ww * 32; base < cnt; base += 2560 * 32) {
            const int e = base + (lane >> 1);
            const bool act = e < cnt;
            const int2 pe = plist[act ? e : (cnt - 1)];
            const int t  = pe.x;
            const int c1 = pe.y & 0xffff, c2 = (pe.y >> 16) & 0xffff;
            const int cand = (lane & 1) ? c2 : c1;
            const float* lrow = latent + (size_t)t * DIMD;
            const float* wr   = embl + (size_t)cand * DIMD;
            const float* qp[LVL > 0 ? LVL : 1];
            #pragma unroll
            for (int j = 0; j < LVL; ++j)
                qp[j] = emb + ((size_t)j * VOC + idx_all[j * NTOK + t]) * DIMD;

            float s_me;
            {
#pragma clang fp contract(off)
                float a0 = 0.f, a1 = 0.f, a2 = 0.f, a3 = 0.f,
                      a4 = 0.f, a5 = 0.f, a6 = 0.f, a7 = 0.f,
                      b0 = 0.f, b1 = 0.f, b2 = 0.f, b3 = 0.f,
                      b4 = 0.f, b5 = 0.f, b6 = 0.f, b7 = 0.f;
                float dot = 0.0f;
                #pragma unroll
                for (int d = 0; d < DIMD; d += 4) {
                    float4 x = *reinterpret_cast<const float4*>(lrow + d);
                    #pragma unroll
                    for (int j = 0; j < LVL; ++j) {
                        const float4 q = *reinterpret_cast<const float4*>(qp[j] + d);
                        x.x -= q.x; x.y -= q.y; x.z -= q.z; x.w -= q.w;
                    }
                    const float4 wv = *reinterpret_cast<const float4*>(wr + d);
                    dot = fmaf(x.x, wv.x, dot);
                    dot = fmaf(x.y, wv.y, dot);
                    dot = fmaf(x.z, wv.z, dot);
                    dot = fmaf(x.w, wv.w, dot);
                    // numpy pairwise: 8 accumulators per 128-half, i ascending
                    const float s0 = x.x * x.x, s1 = x.y * x.y;
                    const float s2 = x.z * x.z, s3 = x.w * x.w;
                    if (d < 128) {
                        if ((d & 7) == 0) { a0 = a0 + s0; a1 = a1 + s1; a2 = a2 + s2; a3 = a3 + s3; }
                        else              { a4 = a4 + s0; a5 = a5 + s1; a6 = a6 + s2; a7 = a7 + s3; }
                    } else {
                        if ((d & 7) == 0) { b0 = b0 + s0; b1 = b1 + s1; b2 = b2 + s2; b3 = b3 + s3; }
                        else              { b4 = b4 + s0; b5 = b5 + s1; b6 = b6 + s2; b7 = b7 + s3; }
                    }
                }
                // tree: ((r0+r1)+(r2+r3))+((r4+r5)+(r6+r7)) per half, then sum
                const float ha = ((a0 + a1) + (a2 + a3)) + ((a4 + a5) + (a6 + a7));
                const float hb = ((b0 + b1) + (b2 + b3)) + ((b4 + b5) + (b6 + b7));
                const float rnv = ha + hb;
                s_me = fmaf(-2.0f, dot, rnv) + wnorml[cand];
            }
            const float s_ot = __shfl_xor(s_me, 1);
            if (act && (lane & 1) == 0) {
                int win;
                if (s_me < s_ot)      win = c1;
                else if (s_ot < s_me) win = c2;
                else                  win = min(c1, c2);
                idxl[t] = (unsigned short)win;
            }
        }
    } else {
        // ---------------- full path: one token per wave ---------------------
        float* rbuf = rbufs[(threadIdx.x >> 6)];
        int cnt = cnts_l[0]; if (cnt > NTOK) cnt = NTOK;
        for (int k = ww - 2560; k < cnt; k += 512) {
            const int t = flist[k];
            float4 a = reinterpret_cast<const float4*>(latent + (size_t)t * DIMD)[lane];
            #pragma unroll
            for (int j = 0; j < LVL; ++j) {
                const float4 q = reinterpret_cast<const float4*>(
                    emb + ((size_t)j * VOC + idx_all[j * NTOK + t]) * DIMD)[lane];
                a.x -= q.x; a.y -= q.y; a.z -= q.z; a.w -= q.w;
            }
            asm volatile("s_waitcnt lgkmcnt(0)" ::: "memory");   // prior reads done
            __builtin_amdgcn_sched_barrier(0);
            reinterpret_cast<float4*>(rbuf)[lane] = a;
            asm volatile("s_waitcnt lgkmcnt(0)" ::: "memory");   // writes visible
            __builtin_amdgcn_sched_barrier(0);
            const float rnv = np_pairnorm_row(rbuf, lane & 15);
            float best = 3.0e38f; int besti = 0x7fffffff;
            for (int j = 0; j < 4; ++j) {
                const float* w0 = embl + (size_t)(j * 256 + lane) * DIMD;
                float a0 = 0.f, a1 = 0.f, a2 = 0.f, a3 = 0.f;
                for (int d = 0; d < DIMD; d += 4) {
                    const float4 r4 = *reinterpret_cast<const float4*>(&rbuf[d]);
                    const float4 v0 = *reinterpret_cast<const float4*>(w0 + d);
                    const float4 v1 = *reinterpret_cast<const float4*>(w0 + 64 * DIMD + d);
                    const float4 v2 = *reinterpret_cast<const float4*>(w0 + 128 * DIMD + d);
                    const float4 v3 = *reinterpret_cast<const float4*>(w0 + 192 * DIMD + d);
                    a0 = fmaf(r4.x, v0.x, a0); a0 = fmaf(r4.y, v0.y, a0);
                    a0 = fmaf(r4.z, v0.z, a0); a0 = fmaf(r4.w, v0.w, a0);
                    a1 = fmaf(r4.x, v1.x, a1); a1 = fmaf(r4.y, v1.y, a1);
                    a1 = fmaf(r4.z, v1.z, a1); a1 = fmaf(r4.w, v1.w, a1);
                    a2 = fmaf(r4.x, v2.x, a2); a2 = fmaf(r4.y, v2.y, a2);
                    a2 = fmaf(r4.z, v2.z, a2); a2 = fmaf(r4.w, v2.w, a2);
                    a3 = fmaf(r4.x, v3.x, a3); a3 = fmaf(r4.y, v3.y, a3);
                    a3 = fmaf(r4.z, v3.z, a3); a3 = fmaf(r4.w, v3.w, a3);
                }
                float s; int c;
                c = j * 256 + lane;        s = fmaf(-2.0f, a0, rnv) + wnorml[c];
                if (s < best) { best = s; besti = c; }
                c = j * 256 + 64 + lane;   s = fmaf(-2.0f, a1, rnv) + wnorml[c];
                if (s < best) { best = s; besti = c; }
                c = j * 256 + 128 + lane;  s = fmaf(-2.0f, a2, rnv) + wnorml[c];
                if (s < best) { best = s; besti = c; }
                c = j * 256 + 192 + lane;  s = fmaf(-2.0f, a3, rnv) + wnorml[c];
                if (s < best) { best = s; besti = c; }
            }
            #pragma unroll
            for (int off = 32; off > 0; off >>= 1) {
                const float ov = __shfl_down(best, off);
                const int   oi = __shfl_down(besti, off);
                if (ov < best || (ov == best && oi < besti)) { best = ov; besti = oi; }
            }
            if (lane == 0) idxl[t] = (unsigned short)besti;
            asm volatile("s_waitcnt lgkmcnt(0)" ::: "memory");   // rbuf reads done
            __builtin_amdgcn_sched_barrier(0);
        }
    }
}

// ---- finale: output (exact code_sum chain) + level-3 loss ------------------
__global__ void k_finale(const float* __restrict__ latent, const float* __restrict__ emb,
                         const unsigned short* __restrict__ idx, float* outq,
                         double* loss_acc)
{
    const int gtid  = blockIdx.x * blockDim.x + threadIdx.x;
    const int gwave = gtid >> 6;
    const int lane  = threadIdx.x & 63;
    const int nwave = (gridDim.x * blockDim.x) >> 6;
    float lsum = 0.0f;
    for (int t = gwave; t < NTOK; t += nwave) {
        const float4 q0 = reinterpret_cast<const float4*>(
            emb + ((size_t)0 * VOC + idx[0 * NTOK + t]) * DIMD)[lane];
        const float4 q1 = reinterpret_cast<const float4*>(
            emb + ((size_t)1 * VOC + idx[1 * NTOK + t]) * DIMD)[lane];
        const float4 q2 = reinterpret_cast<const float4*>(
            emb + ((size_t)2 * VOC + idx[2 * NTOK + t]) * DIMD)[lane];
        const float4 q3 = reinterpret_cast<const float4*>(
            emb + ((size_t)3 * VOC + idx[3 * NTOK + t]) * DIMD)[lane];
        const float4 l4 = reinterpret_cast<const float4*>(latent + (size_t)t * DIMD)[lane];
        float4 o;
        {
            float c, r3, e;
            c = q0.x; c = c + q1.x; c = c + q2.x; c = c + q3.x; o.x = l4.x + (c - l4.x);
            r3 = l4.x - q0.x; r3 = r3 - q1.x; r3 = r3 - q2.x; e = q3.x - r3; lsum += e * e;
            c = q0.y; c = c + q1.y; c = c + q2.y; c = c + q3.y; o.y = l4.y + (c - l4.y);
            r3 = l4.y - q0.y; r3 = r3 - q1.y; r3 = r3 - q2.y; e = q3.y - r3; lsum += e * e;
            c = q0.z; c = c + q1.z; c = c + q2.z; c = c + q3.z; o.z = l4.z + (c - l4.z);
            r3 = l4.z - q0.z; r3 = r3 - q1.z; r3 = r3 - q2.z; e = q3.z - r3; lsum += e * e;
            c = q0.w; c = c + q1.w; c = c + q2.w; c = c + q3.w; o.w = l4.w + (c - l4.w);
            r3 = l4.w - q0.w; r3 = r3 - q1.w; r3 = r3 - q2.w; e = q3.w - r3; lsum += e * e;
        }
        reinterpret_cast<float4*>(outq + (size_t)t * DIMD)[lane] = o;
    }
    #pragma unroll
    for (int off = 32; off > 0; off >>= 1) lsum += __shfl_down(lsum, off);
    if (lane == 0) atomicAdd(loss_acc, (double)lsum);
}

__global__ void k_loss_final(const double* __restrict__ loss_acc, float* __restrict__ out0)
{
    *out0 = (float)(1.25 * (*loss_acc) / ((double)NTOK * (double)DIMD));
}

extern "C" void kernel_launch(void* const* d_in, const int* in_sizes, int n_in,
                              void* d_out, int out_size, void* d_ws, size_t ws_size,
                              hipStream_t stream)
{
    const float* latent = (const float*)d_in[0];
    const float* emb    = (const float*)d_in[1];
    float* out = (float*)d_out;

    char*           ws       = (char*)d_ws;
    double*         loss_acc = (double*)ws;
    int*            cnts     = (int*)(ws + 8);
    float*          wnorm    = (float*)(ws + 64);
    unsigned short* idx      = (unsigned short*)(ws + 16448);
    int*            flist    = (int*)(ws + 540736);
    int2*           plist    = (int2*)(ws + 802880);
    uint4*          wimg     = (uint4*)(ws + 1327168);

    k_wsplit<<<NLEV * 16, 256, 0, stream>>>(emb, wimg, cnts);
    k_pairnorm<<<256, 256, 0, stream>>>(emb, wnorm, NLEV * VOC, loss_acc);

    for (int l = 0; l < NLEV; ++l) {
        unsigned short* idxl = idx + l * NTOK;
        const uint4*    wl   = wimg + (size_t)l * 16 * 2048;
        const float*    wnl  = wnorm + l * VOC;
        int*            cl   = cnts + 2 * l;
        switch (l) {
        case 0:
            k_screen<0><<<NTOK / 128, 256, 0, stream>>>(latent, emb, idx, wl, wnl,
                                                        idxl, plist, flist, cl, loss_acc);
            k_rescue<0><<<768, 256, 0, stream>>>(latent, emb, idx, wnl, plist, flist, cl, idxl);
            break;
        case 1:
            k_screen<1><<<NTOK / 128, 256, 0, stream>>>(latent, emb, idx, wl, wnl,
                                                        idxl, plist, flist, cl, loss_acc);
            k_rescue<1><<<768, 256, 0, stream>>>(latent, emb, idx, wnl, plist, flist, cl, idxl);
            break;
        case 2:
            k_screen<2><<<NTOK / 128, 256, 0, stream>>>(latent, emb, idx, wl, wnl,
                                                        idxl, plist, flist, cl, loss_acc);
            k_rescue<2><<<768, 256, 0, stream>>>(latent, emb, idx, wnl, plist, flist, cl, idxl);
            break;
        default:
            k_screen<3><<<NTOK / 128, 256, 0, stream>>>(latent, emb, idx, wl, wnl,
                                                        idxl, plist, flist, cl, loss_acc);
            k_rescue<3><<<768, 256, 0, stream>>>(latent, emb, idx, wnl, plist, flist, cl, idxl);
            break;
        }
    }
    k_finale<<<1024, 256, 0, stream>>>(latent, emb, idx, out + 1, loss_acc);
    k_loss_final<<<1, 1, 0, stream>>>(loss_acc, out);
}

// Round 18
// 629.392 us; speedup vs baseline: 1.3748x; 1.3748x over previous
//
#include <hip/hip_runtime.h>

#define NTOK 65536
#define DIMD 256
#define VOC  1024
#define NLEV 4
#define TAUP 0.056f   // screened top-2 gap below this -> exact resolution

typedef __attribute__((ext_vector_type(8))) _Float16 f16x8;
typedef __attribute__((ext_vector_type(4))) float f32x4;

// ---------------------------------------------------------------------------
// ws layout:
//   [0]        double loss_acc
//   [8]        int    cnts[8]
//   [64]       float  wnorm[NLEV][VOC]     (16 KB)
//   [16448]    u16    idx[NLEV][NTOK]      (512 KB)
//   [540736]   int    flist[NTOK]          (256 KB)
//   [802880]   int2   plist[NTOK]          (512 KB)
//   [1327168]  uint4  wimg[NLEV*16*2048]   (2 MB)  f16 W, phase-tile order
// Residual never materialized: rebuilt as fl-chain(latent - q0 - ...).
// wimg tile P (codes P*64..+64): 2048 uint4; slot s: frag fi=s>>6 (n=fi>>3,
// k=fi&7), lane=s&63 holds W[P*64+n*16+(lane&15)][k*32+(lane>>4)*8..+8] f16x8.
// ---------------------------------------------------------------------------

__device__ __forceinline__ uint4 cvt8_f16_u(const float4 x0, const float4 x1) {
    union { f16x8 h; uint4 u; } r;
    r.h[0] = (_Float16)x0.x; r.h[1] = (_Float16)x0.y;
    r.h[2] = (_Float16)x0.z; r.h[3] = (_Float16)x0.w;
    r.h[4] = (_Float16)x1.x; r.h[5] = (_Float16)x1.y;
    r.h[6] = (_Float16)x1.z; r.h[7] = (_Float16)x1.w;
    return r.u;
}

__device__ __forceinline__ f16x8 cvt8_f16(const float4 x0, const float4 x1) {
    union { f16x8 h; uint4 u; } r;
    r.h[0] = (_Float16)x0.x; r.h[1] = (_Float16)x0.y;
    r.h[2] = (_Float16)x0.z; r.h[3] = (_Float16)x0.w;
    r.h[4] = (_Float16)x1.x; r.h[5] = (_Float16)x1.y;
    r.h[6] = (_Float16)x1.z; r.h[7] = (_Float16)x1.w;
    return r.h;
}

__device__ __forceinline__ f16x8 u2h(uint4 u) {
    union { uint4 u; f16x8 h; } r; r.u = u; return r.h;
}

__device__ __forceinline__ void gl_lds16(const uint4* g, uint4* l) {
    __builtin_amdgcn_global_load_lds(
        (const __attribute__((address_space(1))) unsigned*)g,
        (__attribute__((address_space(3))) unsigned*)l, 16, 0, 0);
}

__device__ __forceinline__ unsigned med3u(unsigned a, unsigned b, unsigned c) {
    unsigned d;
    asm("v_med3_u32 %0, %1, %2, %3" : "=v"(d) : "v"(a), "v"(b), "v"(c));
    return d;
}

// merge two ascending u32 triples with (value, idx) lexicographic order
__device__ __forceinline__ void merge3u(unsigned& a1, unsigned& a2, unsigned& a3,
                                        int& ai1, int& ai2,
                                        unsigned o1, unsigned o2, unsigned o3,
                                        int oi1, int oi2)
{
    const bool sw = (o1 < a1) || (o1 == a1 && oi1 < ai1);
    const unsigned b1 = sw ? o1 : a1; const int bi1 = sw ? oi1 : ai1;
    const unsigned c1 = sw ? a1 : o1; const int ci1 = sw ? ai1 : oi1;
    const unsigned b2 = sw ? o2 : a2; const int bi2 = sw ? oi2 : ai2;
    const unsigned c2 = sw ? a2 : o2;
    const unsigned b3 = sw ? o3 : a3;
    a1 = b1; ai1 = bi1;
    if (c1 < b2 || (c1 == b2 && ci1 < bi2)) {
        a2 = c1; ai2 = ci1; a3 = min(b2, c2);
    } else {
        a2 = b2; ai2 = bi2; a3 = min(b3, c1);
    }
}

// ------------------- numpy pairwise sum-of-squares (16-lane) ----------------
__device__ __forceinline__ float np_pairnorm_row(const float* row, int j)
{
#pragma clang fp contract(off)
    const int half = j >> 3;
    const int jj   = j & 7;
    const float* a = row + half * 128 + jj;
    float r = a[0] * a[0];
    #pragma unroll
    for (int i = 1; i < 16; ++i) {
        const float x  = a[8 * i];
        const float sq = x * x;
        r = r + sq;
    }
    r = r + __shfl_xor(r, 1);
    r = r + __shfl_xor(r, 2);
    r = r + __shfl_xor(r, 4);
    r = r + __shfl_xor(r, 8);
    return r;
}

// ---------- pre-convert W into phase-tile image + fused wnorm ---------------
__global__ void k_wsplit(const float* __restrict__ emb, uint4* __restrict__ wimg,
                         float* __restrict__ wnorm, double* loss_acc, int* cnts)
{
    if (blockIdx.x == 0 && threadIdx.x == 0) *loss_acc = 0.0;
    if (blockIdx.x == 0 && threadIdx.x < 8) cnts[threadIdx.x] = 0;
    const int l = blockIdx.x >> 4, P = blockIdx.x & 15;   // grid = NLEV*16
    const int tid = threadIdx.x;
    #pragma unroll
    for (int i = 0; i < 8; ++i) {
        const int s  = tid + i * 256;        // 0..2047
        const int fi = s >> 6, ls = s & 63;
        const int n = fi >> 3, k = fi & 7;
        const int code = P * 64 + n * 16 + (ls & 15);
        const float* src = emb + ((size_t)(l * VOC + code)) * DIMD + k * 32 + (ls >> 4) * 8;
        const float4 x0 = *reinterpret_cast<const float4*>(src);
        const float4 x1 = *reinterpret_cast<const float4*>(src + 4);
        wimg[((size_t)(l * 16 + P)) * 2048 + s] = cvt8_f16_u(x0, x1);
    }
    // fused exact numpy wnorm for this tile's 64 codes
    const int lane = tid & 63, w = tid >> 6;
    const int sub = lane >> 4, j = lane & 15;
    #pragma unroll
    for (int it = 0; it < 4; ++it) {
        const int rl  = it * 16 + w * 4 + sub;          // 0..63
        const int row = l * VOC + P * 64 + rl;
        const float v = np_pairnorm_row(emb + (size_t)row * DIMD, j);
        if (j == 0) wnorm[row] = v;
    }
}

#define MFMA16(A, B, C) __builtin_amdgcn_mfma_f32_16x16x32_f16((A), (B), (C), 0, 0, 0)

// ------------- screen (R14 verbatim): LDS dbuf + counted vmcnt --------------
template<int LVL>
__global__ __launch_bounds__(256, 2)
void k_screen(const float* __restrict__ latent, const float* __restrict__ emb,
              const unsigned short* __restrict__ idx_all,
              const uint4* __restrict__ wimg_l, const float* __restrict__ wnorml,
              unsigned short* __restrict__ idxl, int2* __restrict__ plist,
              int* __restrict__ flist, int* cnts_l, double* loss_acc)
{
    __shared__ uint4 ldsB[2][2048];   // 64 KB double-buffered B tile

    const int tid = threadIdx.x, lane = tid & 63, w = tid >> 6;
    const int lr = lane & 15, lg = lane >> 4;
    const int wbase = blockIdx.x * 128 + w * 32;

#define STAGE(pp_, buf_) { \
    const uint4* src_ = wimg_l + (size_t)(pp_) * 2048; \
    _Pragma("unroll") \
    for (int i_ = 0; i_ < 8; ++i_) \
        gl_lds16(src_ + tid + i_ * 256, &ldsB[buf_][tid + i_ * 256]); }

    STAGE(0, 0)

    f16x8 af0_0, af0_1, af0_2, af0_3, af0_4, af0_5, af0_6, af0_7;
    f16x8 af1_0, af1_1, af1_2, af1_3, af1_4, af1_5, af1_6, af1_7;
    float lsum = 0.0f;
    const int t0 = wbase + lr, t1 = wbase + 16 + lr;
    const float* lrow0 = latent + (size_t)t0 * DIMD;
    const float* lrow1 = latent + (size_t)t1 * DIMD;
    const float* qr0[LVL > 0 ? LVL : 1];
    const float* qr1[LVL > 0 ? LVL : 1];
    #pragma unroll
    for (int j = 0; j < LVL; ++j) {
        qr0[j] = emb + ((size_t)j * VOC + idx_all[j * NTOK + t0]) * DIMD;
        qr1[j] = emb + ((size_t)j * VOC + idx_all[j * NTOK + t1]) * DIMD;
    }

#define PRO(m_, dc_) { \
    const int off = (dc_) * 32 + lg * 8; \
    float4 x0 = *reinterpret_cast<const float4*>(lrow##m_ + off); \
    float4 x1 = *reinterpret_cast<const float4*>(lrow##m_ + off + 4); \
    _Pragma("unroll") \
    for (int j = 0; j < LVL; ++j) { \
        const float4 q0 = *reinterpret_cast<const float4*>(qr##m_[j] + off); \
        const float4 q1 = *reinterpret_cast<const float4*>(qr##m_[j] + off + 4); \
        x0.x -= q0.x; x0.y -= q0.y; x0.z -= q0.z; x0.w -= q0.w; \
        x1.x -= q1.x; x1.y -= q1.y; x1.z -= q1.z; x1.w -= q1.w; \
    } \
    if (LVL) { \
        lsum += x0.x * x0.x + x0.y * x0.y + x0.z * x0.z + x0.w * x0.w \
              + x1.x * x1.x + x1.y * x1.y + x1.z * x1.z + x1.w * x1.w; \
    } \
    af##m_##_##dc_ = cvt8_f16(x0, x1); }

    PRO(0, 0) PRO(0, 1) PRO(0, 2) PRO(0, 3) PRO(0, 4) PRO(0, 5) PRO(0, 6) PRO(0, 7)
    PRO(1, 0) PRO(1, 1) PRO(1, 2) PRO(1, 3) PRO(1, 4) PRO(1, 5) PRO(1, 6) PRO(1, 7)
#undef PRO

    if (LVL) {
        #pragma unroll
        for (int o = 32; o; o >>= 1) lsum += __shfl_down(lsum, o);
        if (lane == 0) atomicAdd(loss_acc, (double)lsum);
    }

#define DECLK(m_, r_) unsigned k1_##m_##_##r_ = 0xFFFFFFFFu, \
    k2_##m_##_##r_ = 0xFFFFFFFFu, k3_##m_##_##r_ = 0xFFFFFFFFu;
    DECLK(0, 0) DECLK(0, 1) DECLK(0, 2) DECLK(0, 3)
    DECLK(1, 0) DECLK(1, 1) DECLK(1, 2) DECLK(1, 3)
#undef DECLK

    asm volatile("s_waitcnt vmcnt(0)" ::: "memory");
    __builtin_amdgcn_s_barrier();
    __builtin_amdgcn_sched_barrier(0);

#define KSTEP(k_) { \
    const f16x8 b0 = u2h(LB[((0 * 8) + k_) * 64 + lane]); \
    const f16x8 b1 = u2h(LB[((1 * 8) + k_) * 64 + lane]); \
    const f16x8 b2 = u2h(LB[((2 * 8) + k_) * 64 + lane]); \
    const f16x8 b3 = u2h(LB[((3 * 8) + k_) * 64 + lane]); \
    c00 = MFMA16(af0_##k_, b0, c00); c10 = MFMA16(af1_##k_, b0, c10); \
    c01 = MFMA16(af0_##k_, b1, c01); c11 = MFMA16(af1_##k_, b1, c11); \
    c02 = MFMA16(af0_##k_, b2, c02); c12 = MFMA16(af1_##k_, b2, c12); \
    c03 = MFMA16(af0_##k_, b3, c03); c13 = MFMA16(af1_##k_, b3, c13); }

#define LADD(k1_, k2_, k3_, sval_, cbn_) { \
    const unsigned key_ = (__float_as_uint(sval_) & 0xFFFFFFC0u) | (cbn_); \
    const unsigned nk3_ = med3u(key_, k2_, k3_); \
    const unsigned nk2_ = med3u(k1_, key_, k2_); \
    k1_ = min(k1_, key_); k2_ = nk2_; k3_ = nk3_; }

    for (int p = 0; p < 16; ++p) {
        const int cur = p & 1;
        if (p < 15) {
            STAGE(p + 1, cur ^ 1)
            asm volatile("s_waitcnt vmcnt(8)" ::: "memory");
        } else {
            asm volatile("s_waitcnt vmcnt(0)" ::: "memory");
        }
        __builtin_amdgcn_s_barrier();
        __builtin_amdgcn_sched_barrier(0);

        const uint4* LB = &ldsB[cur][0];
        f32x4 c00 = (f32x4)0.0f, c01 = (f32x4)0.0f, c02 = (f32x4)0.0f, c03 = (f32x4)0.0f;
        f32x4 c10 = (f32x4)0.0f, c11 = (f32x4)0.0f, c12 = (f32x4)0.0f, c13 = (f32x4)0.0f;

        __builtin_amdgcn_s_setprio(1);
        KSTEP(0) KSTEP(1) KSTEP(2) KSTEP(3) KSTEP(4) KSTEP(5) KSTEP(6) KSTEP(7)
        __builtin_amdgcn_s_setprio(0);

        const float wn0 = wnorml[p * 64 + 0 * 16 + lr] + 512.0f;
        const float wn1 = wnorml[p * 64 + 1 * 16 + lr] + 512.0f;
        const float wn2 = wnorml[p * 64 + 2 * 16 + lr] + 512.0f;
        const float wn3 = wnorml[p * 64 + 3 * 16 + lr] + 512.0f;
        const unsigned cb = (unsigned)(p * 4);
#define LADN(m_, cx_, wn_, n_) \
        LADD(k1_##m_##_0, k2_##m_##_0, k3_##m_##_0, fmaf(-2.0f, cx_[0], wn_), cb + n_) \
        LADD(k1_##m_##_1, k2_##m_##_1, k3_##m_##_1, fmaf(-2.0f, cx_[1], wn_), cb + n_) \
        LADD(k1_##m_##_2, k2_##m_##_2, k3_##m_##_2, fmaf(-2.0f, cx_[2], wn_), cb + n_) \
        LADD(k1_##m_##_3, k2_##m_##_3, k3_##m_##_3, fmaf(-2.0f, cx_[3], wn_), cb + n_)
        LADN(0, c00, wn0, 0) LADN(0, c01, wn1, 1) LADN(0, c02, wn2, 2) LADN(0, c03, wn3, 3)
        LADN(1, c10, wn0, 0) LADN(1, c11, wn1, 1) LADN(1, c12, wn2, 2) LADN(1, c13, wn3, 3)
#undef LADN

        asm volatile("s_waitcnt lgkmcnt(0)" ::: "memory");
        __builtin_amdgcn_sched_barrier(0);
        __builtin_amdgcn_s_barrier();
        __builtin_amdgcn_sched_barrier(0);
    }
#undef KSTEP
#undef LADD
#undef STAGE

    unsigned K1[2][4] = {{k1_0_0, k1_0_1, k1_0_2, k1_0_3},
                         {k1_1_0, k1_1_1, k1_1_2, k1_1_3}};
    unsigned K2[2][4] = {{k2_0_0, k2_0_1, k2_0_2, k2_0_3},
                         {k2_1_0, k2_1_1, k2_1_2, k2_1_3}};
    unsigned K3[2][4] = {{k3_0_0, k3_0_1, k3_0_2, k3_0_3},
                         {k3_1_0, k3_1_1, k3_1_2, k3_1_3}};
    #pragma unroll
    for (int m = 0; m < 2; ++m)
        #pragma unroll
        for (int r = 0; r < 4; ++r) {
            unsigned v1 = K1[m][r] & 0xFFFFFFC0u;
            unsigned v2 = K2[m][r] & 0xFFFFFFC0u;
            unsigned v3 = K3[m][r] & 0xFFFFFFC0u;
            int id1 = (int)((K1[m][r] & 63u) << 4) | lr;
            int id2 = (int)((K2[m][r] & 63u) << 4) | lr;
            #pragma unroll
            for (int d = 1; d < 16; d <<= 1) {
                const unsigned o1 = __shfl_xor(v1, d);
                const unsigned o2 = __shfl_xor(v2, d);
                const unsigned o3 = __shfl_xor(v3, d);
                const int     oi1 = __shfl_xor(id1, d);
                const int     oi2 = __shfl_xor(id2, d);
                merge3u(v1, v2, v3, id1, id2, o1, o2, o3, oi1, oi2);
            }
            if (lr == 0) {
                const int gt = wbase + m * 16 + lg * 4 + r;
                idxl[gt] = (unsigned short)id1;
                const float s1 = __uint_as_float(v1);
                const float s2 = __uint_as_float(v2);
                const float s3 = __uint_as_float(v3);
                if (s2 - s1 < TAUP) {
                    if (s3 - s1 >= TAUP) {
                        const int pp = atomicAdd(&cnts_l[1], 1);
                        plist[pp] = make_int2(gt, id1 | (id2 << 16));
                    } else {
                        const int pp = atomicAdd(&cnts_l[0], 1);
                        flist[pp] = gt;
                    }
                }
            }
        }
}

// ---- exact rescue: blocks [0,4096) pair-compare, [4096,4608) full ----------
// Pair path: block-cooperative coalesced staging (residual + both W rows into
// LDS), then two bit-exact serial chains on lanes 0/1 reading LDS.
__global__ void k_rescue(const float* __restrict__ latent, const float* __restrict__ emb,
                         const unsigned short* __restrict__ idx_all, int lev,
                         const float* __restrict__ wnorml,
                         const int2* __restrict__ plist, const int* __restrict__ flist,
                         const int* __restrict__ cnts_l,
                         unsigned short* __restrict__ idxl)
{
    __shared__ float rbuf[DIMD];
    __shared__ float wbuf[2][DIMD];
    const int lane = threadIdx.x;   // blockDim.x == 64
    const float* embl = emb + (size_t)lev * VOC * DIMD;
    if (blockIdx.x < 4096) {
        int cnt = cnts_l[1]; if (cnt > NTOK) cnt = NTOK;
        for (int k = blockIdx.x; k < cnt; k += 4096) {
            const int2 e = plist[k];
            const int t  = e.x;
            const int c1 = e.y & 0xffff, c2 = (e.y >> 16) & 0xffff;
            float4 a = reinterpret_cast<const float4*>(latent + (size_t)t * DIMD)[lane];
            for (int j = 0; j < lev; ++j) {
                const float4 q = reinterpret_cast<const float4*>(
                    emb + ((size_t)j * VOC + idx_all[j * NTOK + t]) * DIMD)[lane];
                a.x -= q.x; a.y -= q.y; a.z -= q.z; a.w -= q.w;
            }
            reinterpret_cast<float4*>(rbuf)[lane] = a;
            reinterpret_cast<float4*>(wbuf[0])[lane] =
                reinterpret_cast<const float4*>(embl + (size_t)c1 * DIMD)[lane];
            reinterpret_cast<float4*>(wbuf[1])[lane] =
                reinterpret_cast<const float4*>(embl + (size_t)c2 * DIMD)[lane];
            __syncthreads();
            const float rnv = np_pairnorm_row(rbuf, lane & 15);
            const int myc = lane ? c2 : c1;
            float acc = 0.0f;
            if (lane < 2) {
                const float* wr = wbuf[lane];
                for (int d = 0; d < DIMD; d += 4) {   // sequential fmaf, d ascending
                    acc = fmaf(rbuf[d + 0], wr[d + 0], acc);
                    acc = fmaf(rbuf[d + 1], wr[d + 1], acc);
                    acc = fmaf(rbuf[d + 2], wr[d + 2], acc);
                    acc = fmaf(rbuf[d + 3], wr[d + 3], acc);
                }
            }
            const float s_l = fmaf(-2.0f, acc, rnv) + wnorml[myc];
            const float s2  = __shfl(s_l, 1);
            if (lane == 0) {
                int win;
                if (s_l < s2)      win = c1;
                else if (s2 < s_l) win = c2;
                else               win = min(c1, c2);
                idxl[t] = (unsigned short)win;
            }
            __syncthreads();
        }
    } else {
        int cnt = cnts_l[0]; if (cnt > NTOK) cnt = NTOK;
        for (int k = blockIdx.x - 4096; k < cnt; k += 512) {
            const int t = flist[k];
            float4 a = reinterpret_cast<const float4*>(latent + (size_t)t * DIMD)[lane];
            for (int j = 0; j < lev; ++j) {
                const float4 q = reinterpret_cast<const float4*>(
                    emb + ((size_t)j * VOC + idx_all[j * NTOK + t]) * DIMD)[lane];
                a.x -= q.x; a.y -= q.y; a.z -= q.z; a.w -= q.w;
            }
            reinterpret_cast<float4*>(rbuf)[lane] = a;
            __syncthreads();
            const float rnv = np_pairnorm_row(rbuf, lane & 15);
            float best = 3.0e38f; int besti = 0x7fffffff;
            for (int j = 0; j < 4; ++j) {
                const float* w0 = embl + (size_t)(j * 256 + lane) * DIMD;
                float a0 = 0.f, a1 = 0.f, a2 = 0.f, a3 = 0.f;
                for (int d = 0; d < DIMD; d += 4) {
                    const float4 r4 = *reinterpret_cast<const float4*>(&rbuf[d]);
                    const float4 v0 = *reinterpret_cast<const float4*>(w0 + d);
                    const float4 v1 = *reinterpret_cast<const float4*>(w0 + 64 * DIMD + d);
                    const float4 v2 = *reinterpret_cast<const float4*>(w0 + 128 * DIMD + d);
                    const float4 v3 = *reinterpret_cast<const float4*>(w0 + 192 * DIMD + d);
                    a0 = fmaf(r4.x, v0.x, a0); a0 = fmaf(r4.y, v0.y, a0);
                    a0 = fmaf(r4.z, v0.z, a0); a0 = fmaf(r4.w, v0.w, a0);
                    a1 = fmaf(r4.x, v1.x, a1); a1 = fmaf(r4.y, v1.y, a1);
                    a1 = fmaf(r4.z, v1.z, a1); a1 = fmaf(r4.w, v1.w, a1);
                    a2 = fmaf(r4.x, v2.x, a2); a2 = fmaf(r4.y, v2.y, a2);
                    a2 = fmaf(r4.z, v2.z, a2); a2 = fmaf(r4.w, v2.w, a2);
                    a3 = fmaf(r4.x, v3.x, a3); a3 = fmaf(r4.y, v3.y, a3);
                    a3 = fmaf(r4.z, v3.z, a3); a3 = fmaf(r4.w, v3.w, a3);
                }
                float s; int c;
                c = j * 256 + lane;        s = fmaf(-2.0f, a0, rnv) + wnorml[c];
                if (s < best) { best = s; besti = c; }
                c = j * 256 + 64 + lane;   s = fmaf(-2.0f, a1, rnv) + wnorml[c];
                if (s < best) { best = s; besti = c; }
                c = j * 256 + 128 + lane;  s = fmaf(-2.0f, a2, rnv) + wnorml[c];
                if (s < best) { best = s; besti = c; }
                c = j * 256 + 192 + lane;  s = fmaf(-2.0f, a3, rnv) + wnorml[c];
                if (s < best) { best = s; besti = c; }
            }
            #pragma unroll
            for (int off = 32; off > 0; off >>= 1) {
                const float ov = __shfl_down(best, off);
                const int   oi = __shfl_down(besti, off);
                if (ov < best || (ov == best && oi < besti)) { best = ov; besti = oi; }
            }
            if (lane == 0) idxl[t] = (unsigned short)besti;
            __syncthreads();
        }
    }
}

// ---- finale: output (exact code_sum chain) + level-3 loss ------------------
__global__ void k_finale(const float* __restrict__ latent, const float* __restrict__ emb,
                         const unsigned short* __restrict__ idx, float* outq,
                         double* loss_acc)
{
    const int gtid  = blockIdx.x * blockDim.x + threadIdx.x;
    const int gwave = gtid >> 6;
    const int lane  = threadIdx.x & 63;
    const int nwave = (gridDim.x * blockDim.x) >> 6;
    float lsum = 0.0f;
    for (int t = gwave; t < NTOK; t += nwave) {
        const float4 q0 = reinterpret_cast<const float4*>(
            emb + ((size_t)0 * VOC + idx[0 * NTOK + t]) * DIMD)[lane];
        const float4 q1 = reinterpret_cast<const float4*>(
            emb + ((size_t)1 * VOC + idx[1 * NTOK + t]) * DIMD)[lane];
        const float4 q2 = reinterpret_cast<const float4*>(
            emb + ((size_t)2 * VOC + idx[2 * NTOK + t]) * DIMD)[lane];
        const float4 q3 = reinterpret_cast<const float4*>(
            emb + ((size_t)3 * VOC + idx[3 * NTOK + t]) * DIMD)[lane];
        const float4 l4 = reinterpret_cast<const float4*>(latent + (size_t)t * DIMD)[lane];
        float4 o;
        {
            float c, r3, e;
            c = q0.x; c = c + q1.x; c = c + q2.x; c = c + q3.x; o.x = l4.x + (c - l4.x);
            r3 = l4.x - q0.x; r3 = r3 - q1.x; r3 = r3 - q2.x; e = q3.x - r3; lsum += e * e;
            c = q0.y; c = c + q1.y; c = c + q2.y; c = c + q3.y; o.y = l4.y + (c - l4.y);
            r3 = l4.y - q0.y; r3 = r3 - q1.y; r3 = r3 - q2.y; e = q3.y - r3; lsum += e * e;
            c = q0.z; c = c + q1.z; c = c + q2.z; c = c + q3.z; o.z = l4.z + (c - l4.z);
            r3 = l4.z - q0.z; r3 = r3 - q1.z; r3 = r3 - q2.z; e = q3.z - r3; lsum += e * e;
            c = q0.w; c = c + q1.w; c = c + q2.w; c = c + q3.w; o.w = l4.w + (c - l4.w);
            r3 = l4.w - q0.w; r3 = r3 - q1.w; r3 = r3 - q2.w; e = q3.w - r3; lsum += e * e;
        }
        reinterpret_cast<float4*>(outq + (size_t)t * DIMD)[lane] = o;
    }
    #pragma unroll
    for (int off = 32; off > 0; off >>= 1) lsum += __shfl_down(lsum, off);
    if (lane == 0) atomicAdd(loss_acc, (double)lsum);
}

__global__ void k_loss_final(const double* __restrict__ loss_acc, float* __restrict__ out0)
{
    *out0 = (float)(1.25 * (*loss_acc) / ((double)NTOK * (double)DIMD));
}

extern "C" void kernel_launch(void* const* d_in, const int* in_sizes, int n_in,
                              void* d_out, int out_size, void* d_ws, size_t ws_size,
                              hipStream_t stream)
{
    const float* latent = (const float*)d_in[0];
    const float* emb    = (const float*)d_in[1];
    float* out = (float*)d_out;

    char*           ws       = (char*)d_ws;
    double*         loss_acc = (double*)ws;
    int*            cnts     = (int*)(ws + 8);
    float*          wnorm    = (float*)(ws + 64);
    unsigned short* idx      = (unsigned short*)(ws + 16448);
    int*            flist    = (int*)(ws + 540736);
    int2*           plist    = (int2*)(ws + 802880);
    uint4*          wimg     = (uint4*)(ws + 1327168);

    k_wsplit<<<NLEV * 16, 256, 0, stream>>>(emb, wimg, wnorm, loss_acc, cnts);

    for (int l = 0; l < NLEV; ++l) {
        unsigned short* idxl = idx + l * NTOK;
        const uint4*    wl   = wimg + (size_t)l * 16 * 2048;
        const float*    wnl  = wnorm + l * VOC;
        int*            cl   = cnts + 2 * l;
        switch (l) {
        case 0: k_screen<0><<<NTOK / 128, 256, 0, stream>>>(latent, emb, idx, wl, wnl,
                                                            idxl, plist, flist, cl, loss_acc); break;
        case 1: k_screen<1><<<NTOK / 128, 256, 0, stream>>>(latent, emb, idx, wl, wnl,
                                                            idxl, plist, flist, cl, loss_acc); break;
        case 2: k_screen<2><<<NTOK / 128, 256, 0, stream>>>(latent, emb, idx, wl, wnl,
                                                            idxl, plist, flist, cl, loss_acc); break;
        default: k_screen<3><<<NTOK / 128, 256, 0, stream>>>(latent, emb, idx, wl, wnl,
                                                             idxl, plist, flist, cl, loss_acc); break;
        }
        k_rescue<<<4608, 64, 0, stream>>>(latent, emb, idx, l, wnl, plist, flist, cl, idxl);
    }
    k_finale<<<1024, 256, 0, stream>>>(latent, emb, idx, out + 1, loss_acc);
    k_loss_final<<<1, 1, 0, stream>>>(loss_acc, out);
}